// Round 1
// baseline (491.805 us; speedup 1.0000x reference)
//
#include <hip/hip_runtime.h>
#include <math.h>

// Problem constants (match reference)
constexpr int Sx    = 2048;
constexpr int Dx    = 512;
constexpr int Hx    = 8;
constexpr int QDx   = 256;
constexpr int HALFx = 128;
constexpr int PKx   = 256;
constexpr int Kx    = 16;
constexpr int HQx   = Hx * QDx;   // 2048
constexpr int Rx    = Sx * Hx;    // 16384 (s,h) rows
constexpr int Ox    = 512;

// ---------------------------------------------------------------------------
// K0: l2-normalize the product keys (2 x 256 rows of 128)
// ---------------------------------------------------------------------------
__global__ __launch_bounds__(64) void knorm_kernel(
    const float* __restrict__ k0, const float* __restrict__ k1,
    float* __restrict__ k0n, float* __restrict__ k1n)
{
    const int row = blockIdx.x;              // 0..511
    const float* src = (row < PKx) ? (k0 + (size_t)row * HALFx)
                                   : (k1 + (size_t)(row - PKx) * HALFx);
    float* dst = (row < PKx) ? (k0n + (size_t)row * HALFx)
                             : (k1n + (size_t)(row - PKx) * HALFx);
    const int t = threadIdx.x;               // 0..63
    float a = src[t];
    float b = src[t + 64];
    float ss = a * a + b * b;
#pragma unroll
    for (int off = 32; off; off >>= 1) ss += __shfl_xor(ss, off);
    float n = sqrtf(ss);
    n = fmaxf(n, 1e-12f);
    dst[t]      = a / n;
    dst[t + 64] = b / n;
}

// ---------------------------------------------------------------------------
// K1: Q = hidden (2048x512) @ Wq^T (512x2048) + bq   -- f32 tiled GEMM
// ---------------------------------------------------------------------------
__global__ __launch_bounds__(256) void qproj_kernel(
    const float* __restrict__ A,   // (Sx, Dx)
    const float* __restrict__ W,   // (HQx, Dx) row-major -> B^T layout
    const float* __restrict__ bq,  // (HQx)
    float* __restrict__ C)         // (Sx, HQx)
{
    constexpr int BM = 64, BN = 64, BK = 32, PAD = 4;
    __shared__ __align__(16) float As[BK][BM + PAD];
    __shared__ __align__(16) float Bs[BK][BN + PAD];
    const int bm = blockIdx.y * BM;
    const int bn = blockIdx.x * BN;
    const int tid = threadIdx.x;
    const int tx = tid & 15;
    const int ty = tid >> 4;
    float acc[4][4] = {{0.f}};
    for (int k0 = 0; k0 < Dx; k0 += BK) {
#pragma unroll
        for (int i = 0; i < (BM * BK) / 256; ++i) {
            int idx = tid + i * 256;
            int m = idx >> 5;
            int k = idx & 31;
            As[k][m] = A[(size_t)(bm + m) * Dx + k0 + k];
            Bs[k][m] = W[(size_t)(bn + m) * Dx + k0 + k];
        }
        __syncthreads();
#pragma unroll
        for (int k = 0; k < BK; ++k) {
            float4 av = *(const float4*)&As[k][ty * 4];
            float4 bv = *(const float4*)&Bs[k][tx * 4];
            float a4[4] = {av.x, av.y, av.z, av.w};
            float b4[4] = {bv.x, bv.y, bv.z, bv.w};
#pragma unroll
            for (int i = 0; i < 4; ++i)
#pragma unroll
                for (int j = 0; j < 4; ++j)
                    acc[i][j] = fmaf(a4[i], b4[j], acc[i][j]);
        }
        __syncthreads();
    }
#pragma unroll
    for (int i = 0; i < 4; ++i) {
        const int row = bm + ty * 4 + i;
#pragma unroll
        for (int j = 0; j < 4; ++j) {
            const int col = bn + tx * 4 + j;
            C[(size_t)row * HQx + col] = acc[i][j] + bq[col];
        }
    }
}

// ---------------------------------------------------------------------------
// K2: LayerNorm(QD=256) + split-half l2norm, in place. One wave per (s,h).
// q row layout: r = s*8+h, row = q + r*256
// ---------------------------------------------------------------------------
__global__ __launch_bounds__(64) void ln_kernel(
    float* __restrict__ q, const float* __restrict__ g,
    const float* __restrict__ b)
{
    const int r = blockIdx.x;                 // 0..16383
    float* row = q + (size_t)r * QDx;
    const int t = threadIdx.x;                // 0..63
    float v0 = row[t], v1 = row[t + 64], v2 = row[t + 128], v3 = row[t + 192];
    float sum = v0 + v1 + v2 + v3;
#pragma unroll
    for (int off = 32; off; off >>= 1) sum += __shfl_xor(sum, off);
    const float mu = sum * (1.f / 256.f);
    float d0 = v0 - mu, d1 = v1 - mu, d2 = v2 - mu, d3 = v3 - mu;
    float ss = d0 * d0 + d1 * d1 + d2 * d2 + d3 * d3;
#pragma unroll
    for (int off = 32; off; off >>= 1) ss += __shfl_xor(ss, off);
    const float var = ss * (1.f / 256.f);
    const float inv = 1.0f / sqrtf(var + 1e-5f);
    v0 = d0 * inv * g[t]       + b[t];
    v1 = d1 * inv * g[t + 64]  + b[t + 64];
    v2 = d2 * inv * g[t + 128] + b[t + 128];
    v3 = d3 * inv * g[t + 192] + b[t + 192];
    // l2norm half 0 (cols 0..127 = {v0,v1}) and half 1 (cols 128..255 = {v2,v3})
    float s0 = v0 * v0 + v1 * v1;
#pragma unroll
    for (int off = 32; off; off >>= 1) s0 += __shfl_xor(s0, off);
    float n0 = fmaxf(sqrtf(s0), 1e-12f);
    float s1 = v2 * v2 + v3 * v3;
#pragma unroll
    for (int off = 32; off; off >>= 1) s1 += __shfl_xor(s1, off);
    float n1 = fmaxf(sqrtf(s1), 1e-12f);
    row[t]       = v0 / n0;
    row[t + 64]  = v1 / n0;
    row[t + 128] = v2 / n1;
    row[t + 192] = v3 / n1;
}

// ---------------------------------------------------------------------------
// K3: scores: S_half = Qn_half (16384x128) @ Kn_half^T (128x256)
// ---------------------------------------------------------------------------
__global__ __launch_bounds__(256) void score_kernel(
    const float* __restrict__ qn,   // (Rx, QDx); half offset selects cols
    const float* __restrict__ k0n, const float* __restrict__ k1n,
    float* __restrict__ s0, float* __restrict__ s1)
{
    constexpr int BM = 64, BN = 64, BK = 32, PAD = 4;
    __shared__ __align__(16) float As[BK][BM + PAD];
    __shared__ __align__(16) float Bs[BK][BN + PAD];
    const int half = blockIdx.z;
    const float* B = half ? k1n : k0n;
    float* Sout = half ? s1 : s0;
    const int bm = blockIdx.y * BM;
    const int bn = blockIdx.x * BN;
    const int tid = threadIdx.x;
    const int tx = tid & 15;
    const int ty = tid >> 4;
    const int coff = half * HALFx;
    float acc[4][4] = {{0.f}};
    for (int k0 = 0; k0 < HALFx; k0 += BK) {
#pragma unroll
        for (int i = 0; i < (BM * BK) / 256; ++i) {
            int idx = tid + i * 256;
            int m = idx >> 5;
            int k = idx & 31;
            As[k][m] = qn[(size_t)(bm + m) * QDx + coff + k0 + k];
            Bs[k][m] = B[(size_t)(bn + m) * HALFx + k0 + k];
        }
        __syncthreads();
#pragma unroll
        for (int k = 0; k < BK; ++k) {
            float4 av = *(const float4*)&As[k][ty * 4];
            float4 bv = *(const float4*)&Bs[k][tx * 4];
            float a4[4] = {av.x, av.y, av.z, av.w};
            float b4[4] = {bv.x, bv.y, bv.z, bv.w};
#pragma unroll
            for (int i = 0; i < 4; ++i)
#pragma unroll
                for (int j = 0; j < 4; ++j)
                    acc[i][j] = fmaf(a4[i], b4[j], acc[i][j]);
        }
        __syncthreads();
    }
#pragma unroll
    for (int i = 0; i < 4; ++i)
#pragma unroll
        for (int j = 0; j < 4; ++j)
            Sout[(size_t)(bm + ty * 4 + i) * PKx + bn + tx * 4 + j] = acc[i][j];
}

// ---------------------------------------------------------------------------
// K4: per (s,h): top-16(s0), top-16(s1), 256 pair-combos, top-16, softmax.
// One wave per row. Each lane holds 4 of 256 values.
// ---------------------------------------------------------------------------
__device__ inline void wave_top16(float v[4], int lane, float* outv, int* outi)
{
#pragma unroll 1
    for (int it = 0; it < 16; ++it) {
        float m = v[0];
        int mi = lane;
#pragma unroll
        for (int j = 1; j < 4; ++j) {
            int idx = lane + 64 * j;
            if (v[j] > m) { m = v[j]; mi = idx; }
        }
#pragma unroll
        for (int off = 32; off; off >>= 1) {
            float om = __shfl_xor(m, off);
            int oi = __shfl_xor(mi, off);
            if (om > m || (om == m && oi < mi)) { m = om; mi = oi; }
        }
        if (lane == 0) { outv[it] = m; outi[it] = mi; }
        if ((mi & 63) == lane) v[mi >> 6] = -INFINITY;   // clear winner
    }
}

__global__ __launch_bounds__(64) void topk_kernel(
    const float* __restrict__ s0g, const float* __restrict__ s1g,
    int* __restrict__ fib, float* __restrict__ wb)
{
    __shared__ float sc0[Kx], sc1[Kx], fsv[Kx];
    __shared__ int ix0[Kx], ix1[Kx], fpos[Kx];
    const int r = blockIdx.x;
    const int lane = threadIdx.x;
    float v[4];
#pragma unroll
    for (int j = 0; j < 4; ++j) v[j] = s0g[(size_t)r * PKx + lane + 64 * j];
    wave_top16(v, lane, sc0, ix0);
#pragma unroll
    for (int j = 0; j < 4; ++j) v[j] = s1g[(size_t)r * PKx + lane + 64 * j];
    wave_top16(v, lane, sc1, ix1);
    __syncthreads();
    // combos: cs[p] = sc0[p>>4] + sc1[p&15]
#pragma unroll
    for (int j = 0; j < 4; ++j) {
        int p = lane + 64 * j;
        v[j] = sc0[p >> 4] + sc1[p & 15];
    }
    wave_top16(v, lane, fsv, fpos);
    __syncthreads();
    // softmax over the 16 winners (replicated across 16-lane groups)
    float f = fsv[lane & 15];
    float mx = f;
#pragma unroll
    for (int off = 8; off; off >>= 1) mx = fmaxf(mx, __shfl_xor(mx, off, 16));
    float e = expf(f - mx);
    float sum = e;
#pragma unroll
    for (int off = 8; off; off >>= 1) sum += __shfl_xor(sum, off, 16);
    if (lane < Kx) {
        int p = fpos[lane];
        fib[(size_t)r * Kx + lane] = ix0[p >> 4] + ix1[p & 15];
        wb[(size_t)r * Kx + lane]  = e / sum;
    }
}

// ---------------------------------------------------------------------------
// K5: expert evaluation. One block per s.
// phase 1: inner[p] = hidden[s]·down[fi_p]; aw[p] = gelu(inner)*w[p]
// phase 2: out[s,o] = sum_p aw[p] * up[fi_p, o]
// ---------------------------------------------------------------------------
__global__ __launch_bounds__(256) void expert_kernel(
    const float* __restrict__ hidden, const float* __restrict__ down,
    const float* __restrict__ up, const int* __restrict__ fib,
    const float* __restrict__ wb, float* __restrict__ out)
{
    __shared__ float hs[Dx];
    __shared__ float aw[Hx * Kx];
    __shared__ int fis[Hx * Kx];
    const int s = blockIdx.x;
    const int tid = threadIdx.x;
    hs[tid]       = hidden[(size_t)s * Dx + tid];
    hs[tid + 256] = hidden[(size_t)s * Dx + tid + 256];
    if (tid < Hx * Kx) fis[tid] = fib[(size_t)s * (Hx * Kx) + tid];
    __syncthreads();
    const int wv = tid >> 6;
    const int lane = tid & 63;
    for (int p = wv; p < Hx * Kx; p += 4) {
        const float* dr = down + (size_t)fis[p] * Dx;
        float acc = 0.f;
#pragma unroll
        for (int i = 0; i < 8; ++i)
            acc = fmaf(hs[lane + 64 * i], dr[lane + 64 * i], acc);
#pragma unroll
        for (int off = 32; off; off >>= 1) acc += __shfl_xor(acc, off);
        if (lane == 0) {
            float x = acc;
            float act = 0.5f * x * (1.f + erff(x * 0.70710678118654752f));
            aw[p] = act * wb[(size_t)s * (Hx * Kx) + p];
        }
    }
    __syncthreads();
    float a0 = 0.f, a1 = 0.f;
    for (int p = 0; p < Hx * Kx; ++p) {
        const float a = aw[p];
        const float* ur = up + (size_t)fis[p] * Ox;
        a0 = fmaf(a, ur[tid], a0);
        a1 = fmaf(a, ur[tid + 256], a1);
    }
    out[(size_t)s * Ox + tid]       = a0;
    out[(size_t)s * Ox + tid + 256] = a1;
}

// ---------------------------------------------------------------------------
extern "C" void kernel_launch(void* const* d_in, const int* in_sizes, int n_in,
                              void* d_out, int out_size, void* d_ws, size_t ws_size,
                              hipStream_t stream)
{
    const float* hidden = (const float*)d_in[0];
    const float* Wq     = (const float*)d_in[1];
    const float* bq     = (const float*)d_in[2];
    const float* ln_g   = (const float*)d_in[3];
    const float* ln_b   = (const float*)d_in[4];
    const float* keys0  = (const float*)d_in[5];
    const float* keys1  = (const float*)d_in[6];
    const float* edown  = (const float*)d_in[7];
    const float* eup    = (const float*)d_in[8];
    float* out = (float*)d_out;

    // workspace layout (floats): ~53 MB total
    float* ws  = (float*)d_ws;
    float* q   = ws;                                  // Sx*HQx        = 4,194,304
    float* k0n = q + (size_t)Sx * HQx;                // PKx*HALFx     = 32,768
    float* k1n = k0n + (size_t)PKx * HALFx;           // 32,768
    float* s0  = k1n + (size_t)PKx * HALFx;           // Rx*PKx        = 4,194,304
    float* s1  = s0 + (size_t)Rx * PKx;               // 4,194,304
    float* wb  = s1 + (size_t)Rx * PKx;               // Rx*Kx         = 262,144
    int*   fib = (int*)(wb + (size_t)Rx * Kx);        // 262,144 ints

    hipLaunchKernelGGL(knorm_kernel, dim3(2 * PKx), dim3(64), 0, stream,
                       keys0, keys1, k0n, k1n);
    hipLaunchKernelGGL(qproj_kernel, dim3(HQx / 64, Sx / 64), dim3(256), 0, stream,
                       hidden, Wq, bq, q);
    hipLaunchKernelGGL(ln_kernel, dim3(Rx), dim3(64), 0, stream, q, ln_g, ln_b);
    hipLaunchKernelGGL(score_kernel, dim3(PKx / 64, Rx / 64, 2), dim3(256), 0, stream,
                       q, k0n, k1n, s0, s1);
    hipLaunchKernelGGL(topk_kernel, dim3(Rx), dim3(64), 0, stream, s0, s1, fib, wb);
    hipLaunchKernelGGL(expert_kernel, dim3(Sx), dim3(256), 0, stream,
                       hidden, edown, eup, fib, wb, out);
}

// Round 2
// 407.163 us; speedup vs baseline: 1.2079x; 1.2079x over previous
//
#include <hip/hip_runtime.h>
#include <math.h>

// Problem constants (match reference)
constexpr int Sx    = 2048;
constexpr int Dx    = 512;
constexpr int Hx    = 8;
constexpr int QDx   = 256;
constexpr int HALFx = 128;
constexpr int PKx   = 256;
constexpr int Kx    = 16;
constexpr int HQx   = Hx * QDx;   // 2048
constexpr int Rx    = Sx * Hx;    // 16384 (s,h) rows
constexpr int Ox    = 512;

// ---------------------------------------------------------------------------
// K0: l2-normalize the product keys (2 x 256 rows of 128)
// ---------------------------------------------------------------------------
__global__ __launch_bounds__(64) void knorm_kernel(
    const float* __restrict__ k0, const float* __restrict__ k1,
    float* __restrict__ k0n, float* __restrict__ k1n)
{
    const int row = blockIdx.x;              // 0..511
    const float* src = (row < PKx) ? (k0 + (size_t)row * HALFx)
                                   : (k1 + (size_t)(row - PKx) * HALFx);
    float* dst = (row < PKx) ? (k0n + (size_t)row * HALFx)
                             : (k1n + (size_t)(row - PKx) * HALFx);
    const int t = threadIdx.x;               // 0..63
    float a = src[t];
    float b = src[t + 64];
    float ss = a * a + b * b;
#pragma unroll
    for (int off = 32; off; off >>= 1) ss += __shfl_xor(ss, off);
    float n = sqrtf(ss);
    n = fmaxf(n, 1e-12f);
    dst[t]      = a / n;
    dst[t + 64] = b / n;
}

// ---------------------------------------------------------------------------
// K1: Q = hidden (2048x512) @ Wq^T (512x2048) + bq   -- f32 tiled GEMM
// ---------------------------------------------------------------------------
__global__ __launch_bounds__(256) void qproj_kernel(
    const float* __restrict__ A,   // (Sx, Dx)
    const float* __restrict__ W,   // (HQx, Dx) row-major -> B^T layout
    const float* __restrict__ bq,  // (HQx)
    float* __restrict__ C)         // (Sx, HQx)
{
    constexpr int BM = 64, BN = 64, BK = 32, PAD = 4;
    __shared__ __align__(16) float As[BK][BM + PAD];
    __shared__ __align__(16) float Bs[BK][BN + PAD];
    const int bm = blockIdx.y * BM;
    const int bn = blockIdx.x * BN;
    const int tid = threadIdx.x;
    const int tx = tid & 15;
    const int ty = tid >> 4;
    float acc[4][4] = {{0.f}};
    for (int k0 = 0; k0 < Dx; k0 += BK) {
#pragma unroll
        for (int i = 0; i < (BM * BK) / 256; ++i) {
            int idx = tid + i * 256;
            int m = idx >> 5;
            int k = idx & 31;
            As[k][m] = A[(size_t)(bm + m) * Dx + k0 + k];
            Bs[k][m] = W[(size_t)(bn + m) * Dx + k0 + k];
        }
        __syncthreads();
#pragma unroll
        for (int k = 0; k < BK; ++k) {
            float4 av = *(const float4*)&As[k][ty * 4];
            float4 bv = *(const float4*)&Bs[k][tx * 4];
            float a4[4] = {av.x, av.y, av.z, av.w};
            float b4[4] = {bv.x, bv.y, bv.z, bv.w};
#pragma unroll
            for (int i = 0; i < 4; ++i)
#pragma unroll
                for (int j = 0; j < 4; ++j)
                    acc[i][j] = fmaf(a4[i], b4[j], acc[i][j]);
        }
        __syncthreads();
    }
#pragma unroll
    for (int i = 0; i < 4; ++i) {
        const int row = bm + ty * 4 + i;
#pragma unroll
        for (int j = 0; j < 4; ++j) {
            const int col = bn + tx * 4 + j;
            C[(size_t)row * HQx + col] = acc[i][j] + bq[col];
        }
    }
}

// ---------------------------------------------------------------------------
// K2: LayerNorm(QD=256) + split-half l2norm, in place. One wave per (s,h).
// ---------------------------------------------------------------------------
__global__ __launch_bounds__(64) void ln_kernel(
    float* __restrict__ q, const float* __restrict__ g,
    const float* __restrict__ b)
{
    const int r = blockIdx.x;                 // 0..16383
    float* row = q + (size_t)r * QDx;
    const int t = threadIdx.x;                // 0..63
    float v0 = row[t], v1 = row[t + 64], v2 = row[t + 128], v3 = row[t + 192];
    float sum = v0 + v1 + v2 + v3;
#pragma unroll
    for (int off = 32; off; off >>= 1) sum += __shfl_xor(sum, off);
    const float mu = sum * (1.f / 256.f);
    float d0 = v0 - mu, d1 = v1 - mu, d2 = v2 - mu, d3 = v3 - mu;
    float ss = d0 * d0 + d1 * d1 + d2 * d2 + d3 * d3;
#pragma unroll
    for (int off = 32; off; off >>= 1) ss += __shfl_xor(ss, off);
    const float var = ss * (1.f / 256.f);
    const float inv = 1.0f / sqrtf(var + 1e-5f);
    v0 = d0 * inv * g[t]       + b[t];
    v1 = d1 * inv * g[t + 64]  + b[t + 64];
    v2 = d2 * inv * g[t + 128] + b[t + 128];
    v3 = d3 * inv * g[t + 192] + b[t + 192];
    float s0 = v0 * v0 + v1 * v1;
#pragma unroll
    for (int off = 32; off; off >>= 1) s0 += __shfl_xor(s0, off);
    float n0 = fmaxf(sqrtf(s0), 1e-12f);
    float s1 = v2 * v2 + v3 * v3;
#pragma unroll
    for (int off = 32; off; off >>= 1) s1 += __shfl_xor(s1, off);
    float n1 = fmaxf(sqrtf(s1), 1e-12f);
    row[t]       = v0 / n0;
    row[t + 64]  = v1 / n0;
    row[t + 128] = v2 / n1;
    row[t + 192] = v3 / n1;
}

// ---------------------------------------------------------------------------
// K3: scores: S_half = Qn_half (16384x128) @ Kn_half^T (128x256)
// ---------------------------------------------------------------------------
__global__ __launch_bounds__(256) void score_kernel(
    const float* __restrict__ qn,
    const float* __restrict__ k0n, const float* __restrict__ k1n,
    float* __restrict__ s0, float* __restrict__ s1)
{
    constexpr int BM = 64, BN = 64, BK = 32, PAD = 4;
    __shared__ __align__(16) float As[BK][BM + PAD];
    __shared__ __align__(16) float Bs[BK][BN + PAD];
    const int half = blockIdx.z;
    const float* B = half ? k1n : k0n;
    float* Sout = half ? s1 : s0;
    const int bm = blockIdx.y * BM;
    const int bn = blockIdx.x * BN;
    const int tid = threadIdx.x;
    const int tx = tid & 15;
    const int ty = tid >> 4;
    const int coff = half * HALFx;
    float acc[4][4] = {{0.f}};
    for (int k0 = 0; k0 < HALFx; k0 += BK) {
#pragma unroll
        for (int i = 0; i < (BM * BK) / 256; ++i) {
            int idx = tid + i * 256;
            int m = idx >> 5;
            int k = idx & 31;
            As[k][m] = qn[(size_t)(bm + m) * QDx + coff + k0 + k];
            Bs[k][m] = B[(size_t)(bn + m) * HALFx + k0 + k];
        }
        __syncthreads();
#pragma unroll
        for (int k = 0; k < BK; ++k) {
            float4 av = *(const float4*)&As[k][ty * 4];
            float4 bv = *(const float4*)&Bs[k][tx * 4];
            float a4[4] = {av.x, av.y, av.z, av.w};
            float b4[4] = {bv.x, bv.y, bv.z, bv.w};
#pragma unroll
            for (int i = 0; i < 4; ++i)
#pragma unroll
                for (int j = 0; j < 4; ++j)
                    acc[i][j] = fmaf(a4[i], b4[j], acc[i][j]);
        }
        __syncthreads();
    }
#pragma unroll
    for (int i = 0; i < 4; ++i)
#pragma unroll
        for (int j = 0; j < 4; ++j)
            Sout[(size_t)(bm + ty * 4 + i) * PKx + bn + tx * 4 + j] = acc[i][j];
}

// ---------------------------------------------------------------------------
// K4: per (s,h) row: top-16(s0), top-16(s1), 256 combos, top-16, softmax.
// One wave per row. Ballot-based radix threshold selection:
//  - map f32 -> order-preserving u32
//  - binary-search the 16th-largest key MSB->LSB using v_cmp+ballot+popc
//    (scalar pipe, no ds_swizzle dependency chains)
//  - extract winners with ballot prefix; exact tie handling fills 16 slots
// ---------------------------------------------------------------------------
__device__ __forceinline__ unsigned fkey(float f) {
    unsigned u = __float_as_uint(f);
    return u ^ ((u & 0x80000000u) ? 0xFFFFFFFFu : 0x80000000u);
}

// Extract exactly 16 entries with key >= T into outv/outi (values + indices).
__device__ __forceinline__ void extract16(
    const float v[4], const unsigned u[4], unsigned T, int lane,
    unsigned long long lmask, float* outv, int* outi)
{
    unsigned long long mg[4];
    int gt_total = 0;
#pragma unroll
    for (int j = 0; j < 4; ++j) {
        mg[j] = __ballot(u[j] > T);
        gt_total += __popcll(mg[j]);
    }
    int bg = 0, be = gt_total;
#pragma unroll
    for (int j = 0; j < 4; ++j) {
        unsigned long long me = __ballot(u[j] == T);
        int idx = lane + 64 * j;
        if (u[j] > T) {
            int pg = bg + __popcll(mg[j] & lmask);
            outv[pg] = v[j]; outi[pg] = idx;
        } else if (u[j] == T) {
            int pe = be + __popcll(me & lmask);
            if (pe < 16) { outv[pe] = v[j]; outi[pe] = idx; }
        }
        bg += __popcll(mg[j]);
        be += __popcll(me);
    }
}

__global__ __launch_bounds__(64) void topk_kernel(
    const float* __restrict__ s0g, const float* __restrict__ s1g,
    int* __restrict__ fib, float* __restrict__ wb)
{
    __shared__ float sc0[Kx], sc1[Kx], fsv[Kx];
    __shared__ int ix0[Kx], ix1[Kx], fid[Kx];
    const int r = blockIdx.x;
    const int lane = threadIdx.x;
    const unsigned long long lmask = (1ull << lane) - 1ull;

    float v0[4], v1[4];
    unsigned u0[4], u1[4];
#pragma unroll
    for (int j = 0; j < 4; ++j) {
        v0[j] = s0g[(size_t)r * PKx + lane + 64 * j];
        v1[j] = s1g[(size_t)r * PKx + lane + 64 * j];
        u0[j] = fkey(v0[j]);
        u1[j] = fkey(v1[j]);
    }

    // interleaved binary search for the 16th-largest key of each half
    unsigned T0 = 0, T1 = 0;
    for (int bit = 31; bit >= 0; --bit) {
        const unsigned c0 = T0 | (1u << bit);
        const unsigned c1 = T1 | (1u << bit);
        int n0 = 0, n1 = 0;
#pragma unroll
        for (int j = 0; j < 4; ++j) {
            n0 += __popcll(__ballot(u0[j] >= c0));
            n1 += __popcll(__ballot(u1[j] >= c1));
        }
        if (n0 >= Kx) T0 = c0;
        if (n1 >= Kx) T1 = c1;
    }
    extract16(v0, u0, T0, lane, lmask, sc0, ix0);
    extract16(v1, u1, T1, lane, lmask, sc1, ix1);
    __syncthreads();

    // 256 pairwise combos: cv[p] = sc0[p>>4] + sc1[p&15]
    float cv[4];
    unsigned cu[4];
    int ci[4];
#pragma unroll
    for (int j = 0; j < 4; ++j) {
        int p = lane + 64 * j;
        cv[j] = sc0[p >> 4] + sc1[p & 15];
        cu[j] = fkey(cv[j]);
        ci[j] = ix0[p >> 4] + ix1[p & 15];  // reference ADDS the two indices
    }
    unsigned T2 = 0;
    for (int bit = 31; bit >= 0; --bit) {
        const unsigned c2 = T2 | (1u << bit);
        int n2 = 0;
#pragma unroll
        for (int j = 0; j < 4; ++j) n2 += __popcll(__ballot(cu[j] >= c2));
        if (n2 >= Kx) T2 = c2;
    }
    // extract final 16 (values + combined expert indices)
    {
        unsigned long long mg[4];
        int gt_total = 0;
#pragma unroll
        for (int j = 0; j < 4; ++j) {
            mg[j] = __ballot(cu[j] > T2);
            gt_total += __popcll(mg[j]);
        }
        int bg = 0, be = gt_total;
#pragma unroll
        for (int j = 0; j < 4; ++j) {
            unsigned long long me = __ballot(cu[j] == T2);
            if (cu[j] > T2) {
                int pg = bg + __popcll(mg[j] & lmask);
                fsv[pg] = cv[j]; fid[pg] = ci[j];
            } else if (cu[j] == T2) {
                int pe = be + __popcll(me & lmask);
                if (pe < 16) { fsv[pe] = cv[j]; fid[pe] = ci[j]; }
            }
            bg += __popcll(mg[j]);
            be += __popcll(me);
        }
    }
    __syncthreads();

    // softmax over the 16 winners (replicated across 16-lane groups)
    float f = fsv[lane & 15];
    float mx = f;
#pragma unroll
    for (int off = 8; off; off >>= 1) mx = fmaxf(mx, __shfl_xor(mx, off, 16));
    float e = expf(f - mx);
    float sum = e;
#pragma unroll
    for (int off = 8; off; off >>= 1) sum += __shfl_xor(sum, off, 16);
    if (lane < Kx) {
        fib[(size_t)r * Kx + lane] = fid[lane];
        wb[(size_t)r * Kx + lane]  = e / sum;
    }
}

// ---------------------------------------------------------------------------
// K5: expert evaluation. One block per s.
// ---------------------------------------------------------------------------
__global__ __launch_bounds__(256) void expert_kernel(
    const float* __restrict__ hidden, const float* __restrict__ down,
    const float* __restrict__ up, const int* __restrict__ fib,
    const float* __restrict__ wb, float* __restrict__ out)
{
    __shared__ float hs[Dx];
    __shared__ float aw[Hx * Kx];
    __shared__ int fis[Hx * Kx];
    const int s = blockIdx.x;
    const int tid = threadIdx.x;
    hs[tid]       = hidden[(size_t)s * Dx + tid];
    hs[tid + 256] = hidden[(size_t)s * Dx + tid + 256];
    if (tid < Hx * Kx) fis[tid] = fib[(size_t)s * (Hx * Kx) + tid];
    __syncthreads();
    const int wv = tid >> 6;
    const int lane = tid & 63;
    for (int p = wv; p < Hx * Kx; p += 4) {
        const float* dr = down + (size_t)fis[p] * Dx;
        float acc = 0.f;
#pragma unroll
        for (int i = 0; i < 8; ++i)
            acc = fmaf(hs[lane + 64 * i], dr[lane + 64 * i], acc);
#pragma unroll
        for (int off = 32; off; off >>= 1) acc += __shfl_xor(acc, off);
        if (lane == 0) {
            float x = acc;
            float act = 0.5f * x * (1.f + erff(x * 0.70710678118654752f));
            aw[p] = act * wb[(size_t)s * (Hx * Kx) + p];
        }
    }
    __syncthreads();
    float a0 = 0.f, a1 = 0.f;
    for (int p = 0; p < Hx * Kx; ++p) {
        const float a = aw[p];
        const float* ur = up + (size_t)fis[p] * Ox;
        a0 = fmaf(a, ur[tid], a0);
        a1 = fmaf(a, ur[tid + 256], a1);
    }
    out[(size_t)s * Ox + tid]       = a0;
    out[(size_t)s * Ox + tid + 256] = a1;
}

// ---------------------------------------------------------------------------
extern "C" void kernel_launch(void* const* d_in, const int* in_sizes, int n_in,
                              void* d_out, int out_size, void* d_ws, size_t ws_size,
                              hipStream_t stream)
{
    const float* hidden = (const float*)d_in[0];
    const float* Wq     = (const float*)d_in[1];
    const float* bq     = (const float*)d_in[2];
    const float* ln_g   = (const float*)d_in[3];
    const float* ln_b   = (const float*)d_in[4];
    const float* keys0  = (const float*)d_in[5];
    const float* keys1  = (const float*)d_in[6];
    const float* edown  = (const float*)d_in[7];
    const float* eup    = (const float*)d_in[8];
    float* out = (float*)d_out;

    float* ws  = (float*)d_ws;
    float* q   = ws;                                  // Sx*HQx
    float* k0n = q + (size_t)Sx * HQx;                // PKx*HALFx
    float* k1n = k0n + (size_t)PKx * HALFx;
    float* s0  = k1n + (size_t)PKx * HALFx;           // Rx*PKx
    float* s1  = s0 + (size_t)Rx * PKx;
    float* wb  = s1 + (size_t)Rx * PKx;               // Rx*Kx
    int*   fib = (int*)(wb + (size_t)Rx * Kx);

    hipLaunchKernelGGL(knorm_kernel, dim3(2 * PKx), dim3(64), 0, stream,
                       keys0, keys1, k0n, k1n);
    hipLaunchKernelGGL(qproj_kernel, dim3(HQx / 64, Sx / 64), dim3(256), 0, stream,
                       hidden, Wq, bq, q);
    hipLaunchKernelGGL(ln_kernel, dim3(Rx), dim3(64), 0, stream, q, ln_g, ln_b);
    hipLaunchKernelGGL(score_kernel, dim3(PKx / 64, Rx / 64, 2), dim3(256), 0, stream,
                       q, k0n, k1n, s0, s1);
    hipLaunchKernelGGL(topk_kernel, dim3(Rx), dim3(64), 0, stream, s0, s1, fib, wb);
    hipLaunchKernelGGL(expert_kernel, dim3(Sx), dim3(256), 0, stream,
                       hidden, edown, eup, fib, wb, out);
}